// Round 1
// baseline (1289.171 us; speedup 1.0000x reference)
//
#include <hip/hip_runtime.h>
#include <hip/hip_bf16.h>
#include <math.h>

// Problem constants
#define BS   32
#define GRID_N 2704
#define A_N  3
#define CH   85
#define VDIM 1024
#define HDIM 512
#define SEL  32
#define ROWS (BS*SEL)          // 1024

// Workspace layout (float element offsets; idx stored as int at base)
#define WS_ISEL   1024
#define WS_VIS    (WS_ISEL + ROWS*VDIM)
#define WS_VIS2   (WS_VIS + ROWS*HDIM)
#define WS_SCORE  (WS_VIS2 + ROWS*HDIM)
#define WS_TOTAL_FLOATS (WS_SCORE + BS*GRID_N)   // ~8.9 MB

// ---------------------------------------------------------------- score (spread over all CUs)
__global__ __launch_bounds__(256) void score_kernel(const float* __restrict__ boxes,
                                                    float* __restrict__ score) {
    int t = blockIdx.x * 256 + threadIdx.x;     // [0, 32*2704)
    const float* p = boxes + (long)t * (A_N * CH);
    score[t] = (p[4] + p[CH + 4] + p[2 * CH + 4]) * (1.0f / 3.0f);
}

// ---------------------------------------------------------------- topk (tournament) + ascending sort
__global__ __launch_bounds__(256) void topk_kernel(const float* __restrict__ score,
                                                   int* __restrict__ idx_out) {
    __shared__ float sc[GRID_N];
    __shared__ float cv[256];
    __shared__ int   ci[256];
    __shared__ int   selg[SEL];
    __shared__ float rbv[4];
    __shared__ int   rbi[4];
    int b = blockIdx.x, tid = threadIdx.x;
    for (int g = tid; g < GRID_N; g += 256) sc[g] = score[b * GRID_N + g];
    __syncthreads();
    // per-thread candidate over its disjoint strided slice
    {
        float bv = -3.4e38f; int bi = 0x7fffffff;
        for (int g = tid; g < GRID_N; g += 256) {
            float v = sc[g];
            if (v > bv || (v == bv && g < bi)) { bv = v; bi = g; }
        }
        cv[tid] = bv; ci[tid] = bi;
    }
    __syncthreads();
    for (int i = 0; i < SEL; ++i) {
        float bv = cv[tid]; int bi = ci[tid];
        for (int off = 32; off; off >>= 1) {
            float ov = __shfl_down(bv, off);
            int   oi = __shfl_down(bi, off);
            if (ov > bv || (ov == bv && oi < bi)) { bv = ov; bi = oi; }
        }
        int lane = tid & 63, wid = tid >> 6;
        if (lane == 0) { rbv[wid] = bv; rbi[wid] = bi; }
        __syncthreads();
        if (tid == 0) {
            float fv = rbv[0]; int fi = rbi[0];
            for (int w = 1; w < 4; ++w)
                if (rbv[w] > fv || (rbv[w] == fv && rbi[w] < fi)) { fv = rbv[w]; fi = rbi[w]; }
            selg[i] = fi;
            sc[fi] = -3.4e38f;          // knockout
        }
        __syncthreads();
        // only the owner of the consumed candidate rescans its slice
        if (ci[tid] == selg[i]) {
            float nv = -3.4e38f; int ni = 0x7fffffff;
            for (int g = tid; g < GRID_N; g += 256) {
                float v = sc[g];
                if (v > nv || (v == nv && g < ni)) { nv = v; ni = g; }
            }
            cv[tid] = nv; ci[tid] = ni;
        }
        __syncthreads();
    }
    if (tid < SEL) {
        int my = selg[tid], rank = 0;
        for (int j = 0; j < SEL; ++j) rank += (selg[j] < my);
        idx_out[b * SEL + rank] = my;
    }
}

// ---------------------------------------------------------------- gather i_sel (done once)
__global__ __launch_bounds__(256) void gather_kernel(const float* __restrict__ xf,
                                                     const int* __restrict__ idx,
                                                     float* __restrict__ isel) {
    int r = blockIdx.x;             // 0..1023
    int b = r >> 5;
    int g = idx[r];
    const float* src = xf + (long)b * VDIM * GRID_N + g;
    float* dst = isel + (long)r * VDIM;
    #pragma unroll
    for (int j = 0; j < 4; ++j) {
        int v = threadIdx.x + j * 256;
        dst[v] = src[(long)v * GRID_N];
    }
}

// ---------------------------------------------------------------- GEMM1: vis = isel @ W_vs + b_vs
// grid (32,8), block 256. Tile 32 rows x 64 cols. KT=128, double-buffered LDS + reg prefetch.
#define KT 128
#define LSTR 33
__global__ __launch_bounds__(256) void gemm1_kernel(const float* __restrict__ A,
                                                    const float* __restrict__ W,
                                                    const float* __restrict__ bias,
                                                    float* __restrict__ out) {
    __shared__ float As[2][KT][LSTR];
    int tid = threadIdx.x;
    int bx = blockIdx.x, by = blockIdx.y;
    int ct = tid & 15, rt = tid >> 4;
    int c0 = by * 64 + ct * 4;
    int r0 = bx * 32 + rt * 2;
    int lrow = tid >> 3;            // 0..31
    int lk0  = (tid & 7) * 4;       // 0..28  (covers 0..127 with j*32 steps)
    const float* arow = A + (long)(bx * 32 + lrow) * VDIM;
    float acc[2][4] = {{0.f,0.f,0.f,0.f},{0.f,0.f,0.f,0.f}};
    float4 pre[4];
    // preload tile 0
    #pragma unroll
    for (int j = 0; j < 4; ++j) pre[j] = *(const float4*)&arow[lk0 + j * 32];
    #pragma unroll
    for (int j = 0; j < 4; ++j) {
        int kk = lk0 + j * 32;
        As[0][kk + 0][lrow] = pre[j].x; As[0][kk + 1][lrow] = pre[j].y;
        As[0][kk + 2][lrow] = pre[j].z; As[0][kk + 3][lrow] = pre[j].w;
    }
    __syncthreads();
    #pragma unroll
    for (int t = 0; t < VDIM / KT; ++t) {
        int buf = t & 1;
        if (t < VDIM / KT - 1) {
            #pragma unroll
            for (int j = 0; j < 4; ++j)
                pre[j] = *(const float4*)&arow[(t + 1) * KT + lk0 + j * 32];
        }
        #pragma unroll 16
        for (int k = 0; k < KT; ++k) {
            float4 w = *(const float4*)&W[(long)(t * KT + k) * HDIM + c0];
            float2 a = *(const float2*)&As[buf][k][2 * rt];
            acc[0][0] += a.x * w.x; acc[0][1] += a.x * w.y;
            acc[0][2] += a.x * w.z; acc[0][3] += a.x * w.w;
            acc[1][0] += a.y * w.x; acc[1][1] += a.y * w.y;
            acc[1][2] += a.y * w.z; acc[1][3] += a.y * w.w;
        }
        if (t < VDIM / KT - 1) {
            #pragma unroll
            for (int j = 0; j < 4; ++j) {
                int kk = lk0 + j * 32;
                As[buf ^ 1][kk + 0][lrow] = pre[j].x; As[buf ^ 1][kk + 1][lrow] = pre[j].y;
                As[buf ^ 1][kk + 2][lrow] = pre[j].z; As[buf ^ 1][kk + 3][lrow] = pre[j].w;
            }
        }
        __syncthreads();
    }
    float4 bv = *(const float4*)&bias[c0];
    #pragma unroll
    for (int i = 0; i < 2; ++i) {
        float4 o;
        o.x = acc[i][0] + bv.x; o.y = acc[i][1] + bv.y;
        o.z = acc[i][2] + bv.z; o.w = acc[i][3] + bv.w;
        *(float4*)&out[(long)(r0 + i) * HDIM + c0] = o;
    }
}

// ---------------------------------------------------------------- GEMM2 (logits fused):
// vis2 = [vis*w0 | tag*w1] @ [Wvp; Wtag] + bvp + btag + pos
__global__ __launch_bounds__(256) void gemm2_kernel(const float* __restrict__ vis,
                                                    const float* __restrict__ tag,
                                                    const float* __restrict__ pos,
                                                    const float* __restrict__ Wsoft,
                                                    const float* __restrict__ bsoft,
                                                    const float* __restrict__ Wvp,
                                                    const float* __restrict__ Wtag,
                                                    const float* __restrict__ bvp,
                                                    const float* __restrict__ btag,
                                                    float* __restrict__ out) {
    __shared__ float As[2][KT][LSTR];
    __shared__ float w0s[32];
    __shared__ float w1s[32];
    int tid = threadIdx.x;
    int bx = blockIdx.x, by = blockIdx.y;
    int ct = tid & 15, rt = tid >> 4;
    int c0 = by * 64 + ct * 4;
    int r0 = bx * 32 + rt * 2;
    int lrow = tid >> 3;            // 0..31
    int lk0  = (tid & 7) * 4;       // 0..28
    int grow = bx * 32 + lrow;
    const float* vrow = vis + (long)grow * HDIM;
    const float* trow = tag + (long)grow * HDIM;

    // ---- fused logits: 8 lanes per row, 64 k's per lane ----
    {
        int sub = tid & 7;
        const float* vr = vrow + sub * 64;
        const float* tr = trow + sub * 64;
        const float* pr = pos + (long)grow * HDIM + sub * 64;
        const float* wr = Wsoft + (sub * 64) * 2;
        float s0 = 0.f, s1 = 0.f;
        #pragma unroll
        for (int j = 0; j < 16; ++j) {
            float4 v = *(const float4*)&vr[j * 4];
            float4 t = *(const float4*)&tr[j * 4];
            float4 p = *(const float4*)&pr[j * 4];
            float4 wA = *(const float4*)&wr[j * 8];
            float4 wB = *(const float4*)&wr[j * 8 + 4];
            float e0 = v.x + t.x + p.x, e1 = v.y + t.y + p.y;
            float e2 = v.z + t.z + p.z, e3 = v.w + t.w + p.w;
            s0 += e0 * wA.x + e1 * wA.z + e2 * wB.x + e3 * wB.z;
            s1 += e0 * wA.y + e1 * wA.w + e2 * wB.y + e3 * wB.w;
        }
        s0 += __shfl_down(s0, 4, 8); s1 += __shfl_down(s1, 4, 8);
        s0 += __shfl_down(s0, 2, 8); s1 += __shfl_down(s1, 2, 8);
        s0 += __shfl_down(s0, 1, 8); s1 += __shfl_down(s1, 1, 8);
        if (sub == 0) {
            float l0 = (s0 + bsoft[0]) * (1.0f / 0.03f);
            float l1 = (s1 + bsoft[1]) * (1.0f / 0.03f);
            float m = fmaxf(l0, l1);
            float lse = m + logf(expf(l0 - m) + expf(l1 - m));
            w0s[lrow] = l0 - lse;
            w1s[lrow] = l1 - lse;
        }
    }
    __syncthreads();
    float sw0 = w0s[lrow], sw1 = w1s[lrow];

    const int NT = (2 * HDIM) / KT;    // 8 tiles; 0-3 from vis, 4-7 from tag
    float acc[2][4] = {{0.f,0.f,0.f,0.f},{0.f,0.f,0.f,0.f}};
    float4 pre[4];
    #pragma unroll
    for (int j = 0; j < 4; ++j) pre[j] = *(const float4*)&vrow[lk0 + j * 32];
    #pragma unroll
    for (int j = 0; j < 4; ++j) {
        int kk = lk0 + j * 32;
        As[0][kk + 0][lrow] = pre[j].x * sw0; As[0][kk + 1][lrow] = pre[j].y * sw0;
        As[0][kk + 2][lrow] = pre[j].z * sw0; As[0][kk + 3][lrow] = pre[j].w * sw0;
    }
    __syncthreads();
    #pragma unroll
    for (int t = 0; t < NT; ++t) {
        int buf = t & 1;
        float sn = 0.f;
        if (t < NT - 1) {
            int kg = (t + 1) * KT;     // global k of next tile
            const float* srow = (kg < HDIM) ? (vrow + kg) : (trow + kg - HDIM);
            sn = (kg < HDIM) ? sw0 : sw1;
            #pragma unroll
            for (int j = 0; j < 4; ++j)
                pre[j] = *(const float4*)&srow[lk0 + j * 32];
        }
        const float* Wb = (t * KT < HDIM) ? (Wvp + (long)(t * KT) * HDIM)
                                          : (Wtag + (long)(t * KT - HDIM) * HDIM);
        #pragma unroll 16
        for (int k = 0; k < KT; ++k) {
            float4 w = *(const float4*)&Wb[(long)k * HDIM + c0];
            float2 a = *(const float2*)&As[buf][k][2 * rt];
            acc[0][0] += a.x * w.x; acc[0][1] += a.x * w.y;
            acc[0][2] += a.x * w.z; acc[0][3] += a.x * w.w;
            acc[1][0] += a.y * w.x; acc[1][1] += a.y * w.y;
            acc[1][2] += a.y * w.z; acc[1][3] += a.y * w.w;
        }
        if (t < NT - 1) {
            #pragma unroll
            for (int j = 0; j < 4; ++j) {
                int kk = lk0 + j * 32;
                As[buf ^ 1][kk + 0][lrow] = pre[j].x * sn; As[buf ^ 1][kk + 1][lrow] = pre[j].y * sn;
                As[buf ^ 1][kk + 2][lrow] = pre[j].z * sn; As[buf ^ 1][kk + 3][lrow] = pre[j].w * sn;
            }
        }
        __syncthreads();
    }
    float4 b1 = *(const float4*)&bvp[c0];
    float4 b2 = *(const float4*)&btag[c0];
    #pragma unroll
    for (int i = 0; i < 2; ++i) {
        int r = r0 + i;
        float4 p = *(const float4*)&pos[(long)r * HDIM + c0];
        float4 o;
        o.x = acc[i][0] + b1.x + b2.x + p.x;
        o.y = acc[i][1] + b1.y + b2.y + p.y;
        o.z = acc[i][2] + b1.z + b2.z + p.z;
        o.w = acc[i][3] + b1.w + b2.w + p.w;
        *(float4*)&out[(long)r * HDIM + c0] = o;
    }
}

// ---------------------------------------------------------------- final (lang proj fused)
__global__ __launch_bounds__(256) void final_kernel(const float* __restrict__ vis2,
                                                    const float* __restrict__ lang,
                                                    const float* __restrict__ Wts,
                                                    const float* __restrict__ bts,
                                                    const int* __restrict__ idx,
                                                    const float* __restrict__ boxes,
                                                    float* __restrict__ out) {
    __shared__ float ll[HDIM];
    __shared__ float lns[HDIM];
    __shared__ float red[4];
    __shared__ float sims[SEL];
    int b = blockIdx.x, tid = threadIdx.x;
    int lane = tid & 63, wid = tid >> 6;
    ll[tid]       = lang[b * HDIM + tid];
    ll[tid + 256] = lang[b * HDIM + tid + 256];
    __syncthreads();
    for (int h = tid; h < HDIM; h += 256) {
        // 4 independent accumulators: break the 512-long serial FMA chain
        float a0 = 0.f, a1 = 0.f, a2 = 0.f, a3 = 0.f;
        for (int k = 0; k < HDIM; k += 4) {
            a0 += ll[k + 0] * Wts[(long)(k + 0) * HDIM + h];
            a1 += ll[k + 1] * Wts[(long)(k + 1) * HDIM + h];
            a2 += ll[k + 2] * Wts[(long)(k + 2) * HDIM + h];
            a3 += ll[k + 3] * Wts[(long)(k + 3) * HDIM + h];
        }
        lns[h] = ((a0 + a1) + (a2 + a3)) + bts[h];
    }
    __syncthreads();
    float s = lns[tid] * lns[tid] + lns[tid + 256] * lns[tid + 256];
    for (int off = 32; off; off >>= 1) s += __shfl_down(s, off);
    if (lane == 0) red[wid] = s;
    __syncthreads();
    float sscale;
    {
        float t = red[0] + red[1] + red[2] + red[3];
        sscale = 1.0f / (sqrtf(t) + 1e-8f);
    }
    for (int j = 0; j < 8; ++j) {
        int sl = wid + j * 4;
        const float* vr = vis2 + (long)(b * SEL + sl) * HDIM;
        int k = lane * 8;
        float ss = 0.f, dot = 0.f;
        #pragma unroll
        for (int t = 0; t < 8; ++t) {
            float v = vr[k + t];
            ss += v * v;
            dot += v * lns[k + t];
        }
        for (int off = 32; off; off >>= 1) {
            ss += __shfl_down(ss, off);
            dot += __shfl_down(dot, off);
        }
        if (lane == 0) {
            float sim = dot * sscale / (sqrtf(ss) + 1e-8f);
            out[BS * 5 + b * SEL + sl] = sim;
            sims[sl] = sim;
        }
    }
    __syncthreads();
    if (tid == 0) {
        int bsi = 0; float bvv = sims[0];
        for (int sl = 1; sl < SEL; ++sl)
            if (sims[sl] > bvv) { bvv = sims[sl]; bsi = sl; }
        int g = idx[b * SEL + bsi];
        const float* bb = boxes + ((long)(b * GRID_N + g)) * A_N * CH;
        float o0 = bb[4], o1 = bb[CH + 4], o2 = bb[2 * CH + 4];
        int j = 0; float ov = o0;
        if (o1 > ov) { ov = o1; j = 1; }
        if (o2 > ov) { ov = o2; j = 2; }
        const float* sb = bb + j * CH;
        float x = sb[0], y = sb[1], w = sb[2], h = sb[3];
        float x1 = x - w * 0.5f, y1 = y - h * 0.5f;
        out[b * 5 + 0] = x1;
        out[b * 5 + 1] = y1;
        out[b * 5 + 2] = x1 + w;
        out[b * 5 + 3] = y1 + h;
        out[b * 5 + 4] = sb[4];
    }
}

// ---------------------------------------------------------------- launch
extern "C" void kernel_launch(void* const* d_in, const int* in_sizes, int n_in,
                              void* d_out, int out_size, void* d_ws, size_t ws_size,
                              hipStream_t stream) {
    const float* boxes    = (const float*)d_in[0];
    const float* x_feat   = (const float*)d_in[1];
    const float* tag_emb  = (const float*)d_in[2];
    const float* pos_emb  = (const float*)d_in[3];
    const float* lang     = (const float*)d_in[4];
    const float* W_vs     = (const float*)d_in[5];
    const float* b_vs     = (const float*)d_in[6];
    const float* W_ts     = (const float*)d_in[7];
    const float* b_ts     = (const float*)d_in[8];
    const float* W_vs_pos = (const float*)d_in[9];
    const float* b_vs_pos = (const float*)d_in[10];
    const float* W_tag    = (const float*)d_in[11];
    const float* b_tag    = (const float*)d_in[12];
    const float* W_soft   = (const float*)d_in[13];
    const float* b_soft   = (const float*)d_in[14];
    float* out = (float*)d_out;

    if (ws_size < (size_t)WS_TOTAL_FLOATS * sizeof(float)) return;

    float* wsf   = (float*)d_ws;
    int*   wsidx = (int*)d_ws;             // 1024 ints at base
    float* isel  = wsf + WS_ISEL;
    float* vis   = wsf + WS_VIS;
    float* vis2  = wsf + WS_VIS2;
    float* score = wsf + WS_SCORE;

    score_kernel<<<(BS * GRID_N) / 256, 256, 0, stream>>>(boxes, score);
    topk_kernel<<<BS, 256, 0, stream>>>(score, wsidx);
    gather_kernel<<<ROWS, 256, 0, stream>>>(x_feat, wsidx, isel);
    gemm1_kernel<<<dim3(32, 8), 256, 0, stream>>>(isel, W_vs, b_vs, vis);
    gemm2_kernel<<<dim3(32, 8), 256, 0, stream>>>(vis, tag_emb, pos_emb, W_soft, b_soft,
                                                  W_vs_pos, W_tag, b_vs_pos, b_tag, vis2);
    final_kernel<<<BS, 256, 0, stream>>>(vis2, lang, W_ts, b_ts, wsidx, boxes, out);
}

// Round 2
// 648.360 us; speedup vs baseline: 1.9884x; 1.9884x over previous
//
#include <hip/hip_runtime.h>
#include <hip/hip_bf16.h>
#include <math.h>

// Problem constants
#define BS   32
#define GRID_N 2704
#define A_N  3
#define CH   85
#define VDIM 1024
#define HDIM 512
#define SEL  32
#define ROWS (BS*SEL)          // 1024

// Workspace layout (float element offsets; idx stored as int at base)
#define WS_ISEL   1024
#define WS_VIS    (WS_ISEL + ROWS*VDIM)
#define WS_VIS2   (WS_VIS + ROWS*HDIM)
#define WS_SCORE  (WS_VIS2 + ROWS*HDIM)
#define WS_W01    (WS_SCORE + BS*GRID_N)
#define WS_TOTAL_FLOATS (WS_W01 + ROWS*2)   // ~8.9 MB

// ---------------------------------------------------------------- score (spread over all CUs)
__global__ __launch_bounds__(256) void score_kernel(const float* __restrict__ boxes,
                                                    float* __restrict__ score) {
    int t = blockIdx.x * 256 + threadIdx.x;     // [0, 32*2704)
    const float* p = boxes + (long)t * (A_N * CH);
    score[t] = (p[4] + p[CH + 4] + p[2 * CH + 4]) * (1.0f / 3.0f);
}

// ---------------------------------------------------------------- topk (tournament) + ascending sort
__global__ __launch_bounds__(256) void topk_kernel(const float* __restrict__ score,
                                                   int* __restrict__ idx_out) {
    __shared__ float sc[GRID_N];
    __shared__ float cv[256];
    __shared__ int   ci[256];
    __shared__ int   selg[SEL];
    __shared__ float rbv[4];
    __shared__ int   rbi[4];
    int b = blockIdx.x, tid = threadIdx.x;
    for (int g = tid; g < GRID_N; g += 256) sc[g] = score[b * GRID_N + g];
    __syncthreads();
    {
        float bv = -3.4e38f; int bi = 0x7fffffff;
        for (int g = tid; g < GRID_N; g += 256) {
            float v = sc[g];
            if (v > bv || (v == bv && g < bi)) { bv = v; bi = g; }
        }
        cv[tid] = bv; ci[tid] = bi;
    }
    __syncthreads();
    for (int i = 0; i < SEL; ++i) {
        float bv = cv[tid]; int bi = ci[tid];
        for (int off = 32; off; off >>= 1) {
            float ov = __shfl_down(bv, off);
            int   oi = __shfl_down(bi, off);
            if (ov > bv || (ov == bv && oi < bi)) { bv = ov; bi = oi; }
        }
        int lane = tid & 63, wid = tid >> 6;
        if (lane == 0) { rbv[wid] = bv; rbi[wid] = bi; }
        __syncthreads();
        if (tid == 0) {
            float fv = rbv[0]; int fi = rbi[0];
            for (int w = 1; w < 4; ++w)
                if (rbv[w] > fv || (rbv[w] == fv && rbi[w] < fi)) { fv = rbv[w]; fi = rbi[w]; }
            selg[i] = fi;
            sc[fi] = -3.4e38f;          // knockout
        }
        __syncthreads();
        if (ci[tid] == selg[i]) {       // only the consumed owner rescans
            float nv = -3.4e38f; int ni = 0x7fffffff;
            for (int g = tid; g < GRID_N; g += 256) {
                float v = sc[g];
                if (v > nv || (v == nv && g < ni)) { nv = v; ni = g; }
            }
            cv[tid] = nv; ci[tid] = ni;
        }
        __syncthreads();
    }
    if (tid < SEL) {
        int my = selg[tid], rank = 0;
        for (int j = 0; j < SEL; ++j) rank += (selg[j] < my);
        idx_out[b * SEL + rank] = my;
    }
}

// ---------------------------------------------------------------- gather i_sel
__global__ __launch_bounds__(256) void gather_kernel(const float* __restrict__ xf,
                                                     const int* __restrict__ idx,
                                                     float* __restrict__ isel) {
    int r = blockIdx.x;             // 0..1023
    int b = r >> 5;
    int g = idx[r];
    const float* src = xf + (long)b * VDIM * GRID_N + g;
    float* dst = isel + (long)r * VDIM;
    #pragma unroll
    for (int j = 0; j < 4; ++j) {
        int v = threadIdx.x + j * 256;
        dst[v] = src[(long)v * GRID_N];
    }
}

// ---------------------------------------------------------------- w01: per-row log-softmax weights
// logits = ((vis+tag+pos) @ Wsoft + bsoft)/0.03 ; w01 = log_softmax(logits)
__global__ __launch_bounds__(256) void w01_kernel(const float* __restrict__ vis,
                                                  const float* __restrict__ tag,
                                                  const float* __restrict__ pos,
                                                  const float* __restrict__ Wsoft,
                                                  const float* __restrict__ bsoft,
                                                  float* __restrict__ w01) {
    int tid = threadIdx.x;
    int lane = tid & 63;
    int r = blockIdx.x * 4 + (tid >> 6);     // one wave per row
    int k0 = lane * 8;
    const float* vr = vis + (long)r * HDIM + k0;
    const float* tr = tag + (long)r * HDIM + k0;
    const float* pr = pos + (long)r * HDIM + k0;
    const float* wr = Wsoft + 2 * k0;
    float s0 = 0.f, s1 = 0.f;
    #pragma unroll
    for (int j = 0; j < 2; ++j) {
        float4 v = *(const float4*)&vr[j * 4];
        float4 t = *(const float4*)&tr[j * 4];
        float4 p = *(const float4*)&pr[j * 4];
        float4 wA = *(const float4*)&wr[j * 8];
        float4 wB = *(const float4*)&wr[j * 8 + 4];
        float e0 = v.x + t.x + p.x, e1 = v.y + t.y + p.y;
        float e2 = v.z + t.z + p.z, e3 = v.w + t.w + p.w;
        s0 += e0 * wA.x + e1 * wA.z + e2 * wB.x + e3 * wB.z;
        s1 += e0 * wA.y + e1 * wA.w + e2 * wB.y + e3 * wB.w;
    }
    #pragma unroll
    for (int off = 32; off; off >>= 1) {
        s0 += __shfl_down(s0, off);
        s1 += __shfl_down(s1, off);
    }
    if (lane == 0) {
        float l0 = (s0 + bsoft[0]) * (1.0f / 0.03f);
        float l1 = (s1 + bsoft[1]) * (1.0f / 0.03f);
        float m = fmaxf(l0, l1);
        float lse = m + logf(expf(l0 - m) + expf(l1 - m));
        *(float2*)&w01[r * 2] = make_float2(l0 - lse, l1 - lse);
    }
}

// ================================================================ GEMM core
// 512 threads = 2 split-K groups of 256. Tile 32 rows x 64 cols, KT=32, double-buffered LDS
// for BOTH operands (W tile XOR-swizzled by k to kill stride-64 ds_write conflicts).
// Inner loop is LDS-only; global loads only stage the next tile.
#define KT 32
// swizzled float index of granule gi (0..15) in row k of a W tile
#define WIDX(k, gi) (((k) * 64) + (((gi) ^ ((k) & 7)) << 2))

// ---------------------------------------------------------------- GEMM1: vis = isel @ W_vs + b_vs
__global__ __launch_bounds__(512) void gemm1_kernel(const float* __restrict__ A,
                                                    const float* __restrict__ W,
                                                    const float* __restrict__ bias,
                                                    float* __restrict__ out) {
    __shared__ float As[2][2][KT][34];
    __shared__ float Ws[2][2][KT * 64];
    __shared__ float Rs[32][68];
    int tid = threadIdx.x;
    int g = tid >> 8;                 // split-K group 0/1
    int tg = tid & 255;
    int bx = blockIdx.x, by = blockIdx.y;
    int ct = tg & 15, rt = tg >> 4;   // compute mapping: cols ct*4.., rows rt*2..
    int c0 = by * 64 + ct * 4;
    // staging mapping
    int srow = tg >> 3;               // 0..31
    int sk4  = (tg & 7) * 4;          // 0..28
    int wk = tg >> 3;                 // 0..31 (k in tile)
    int wg0 = (tg & 7) * 2;           // granule 0..14 (even)
    const long kbase = (long)g * 512;
    const float* arow = A + (long)(bx * 32 + srow) * VDIM + kbase;
    const float* wbase = W + kbase * HDIM + by * 64;
    float* wsg = &Ws[g][0][0];

    float acc[2][4] = {{0.f,0.f,0.f,0.f},{0.f,0.f,0.f,0.f}};
    {   // stage tile 0
        float4 a0  = *(const float4*)&arow[sk4];
        float4 w0v = *(const float4*)&wbase[(long)wk * HDIM + wg0 * 4];
        float4 w1v = *(const float4*)&wbase[(long)wk * HDIM + wg0 * 4 + 4];
        As[g][0][sk4 + 0][srow] = a0.x; As[g][0][sk4 + 1][srow] = a0.y;
        As[g][0][sk4 + 2][srow] = a0.z; As[g][0][sk4 + 3][srow] = a0.w;
        *(float4*)&wsg[WIDX(wk, wg0)]     = w0v;
        *(float4*)&wsg[WIDX(wk, wg0 + 1)] = w1v;
    }
    __syncthreads();
    for (int t = 0; t < 16; ++t) {
        int buf = t & 1;
        float4 na, nw0, nw1;
        if (t < 15) {
            na  = *(const float4*)&arow[(t + 1) * KT + sk4];
            nw0 = *(const float4*)&wbase[(long)((t + 1) * KT + wk) * HDIM + wg0 * 4];
            nw1 = *(const float4*)&wbase[(long)((t + 1) * KT + wk) * HDIM + wg0 * 4 + 4];
        }
        const float* wsb = &Ws[g][buf][0];
        #pragma unroll
        for (int k = 0; k < KT; ++k) {
            float4 w = *(const float4*)&wsb[WIDX(k, ct)];
            float2 a = *(const float2*)&As[g][buf][k][rt * 2];
            acc[0][0] += a.x * w.x; acc[0][1] += a.x * w.y;
            acc[0][2] += a.x * w.z; acc[0][3] += a.x * w.w;
            acc[1][0] += a.y * w.x; acc[1][1] += a.y * w.y;
            acc[1][2] += a.y * w.z; acc[1][3] += a.y * w.w;
        }
        if (t < 15) {
            float* wsn = &Ws[g][buf ^ 1][0];
            As[g][buf ^ 1][sk4 + 0][srow] = na.x; As[g][buf ^ 1][sk4 + 1][srow] = na.y;
            As[g][buf ^ 1][sk4 + 2][srow] = na.z; As[g][buf ^ 1][sk4 + 3][srow] = na.w;
            *(float4*)&wsn[WIDX(wk, wg0)]     = nw0;
            *(float4*)&wsn[WIDX(wk, wg0 + 1)] = nw1;
        }
        __syncthreads();
    }
    if (g == 1) {
        *(float4*)&Rs[rt * 2 + 0][ct * 4] = make_float4(acc[0][0], acc[0][1], acc[0][2], acc[0][3]);
        *(float4*)&Rs[rt * 2 + 1][ct * 4] = make_float4(acc[1][0], acc[1][1], acc[1][2], acc[1][3]);
    }
    __syncthreads();
    if (g == 0) {
        float4 bv = *(const float4*)&bias[c0];
        #pragma unroll
        for (int i = 0; i < 2; ++i) {
            float4 r = *(const float4*)&Rs[rt * 2 + i][ct * 4];
            float4 o;
            o.x = acc[i][0] + r.x + bv.x; o.y = acc[i][1] + r.y + bv.y;
            o.z = acc[i][2] + r.z + bv.z; o.w = acc[i][3] + r.w + bv.w;
            *(float4*)&out[(long)(bx * 32 + rt * 2 + i) * HDIM + c0] = o;
        }
    }
}

// ---------------------------------------------------------------- GEMM2:
// vis2 = (vis*w0) @ Wvp + (tag*w1) @ Wtag + bvp + btag + pos
// group 0 handles the vis*w0 half, group 1 the tag*w1 half.
__global__ __launch_bounds__(512) void gemm2_kernel(const float* __restrict__ vis,
                                                    const float* __restrict__ tag,
                                                    const float* __restrict__ pos,
                                                    const float* __restrict__ w01,
                                                    const float* __restrict__ Wvp,
                                                    const float* __restrict__ Wtag,
                                                    const float* __restrict__ bvp,
                                                    const float* __restrict__ btag,
                                                    float* __restrict__ out) {
    __shared__ float As[2][2][KT][34];
    __shared__ float Ws[2][2][KT * 64];
    __shared__ float Rs[32][68];
    int tid = threadIdx.x;
    int g = tid >> 8;
    int tg = tid & 255;
    int bx = blockIdx.x, by = blockIdx.y;
    int ct = tg & 15, rt = tg >> 4;
    int c0 = by * 64 + ct * 4;
    int srow = tg >> 3;
    int sk4  = (tg & 7) * 4;
    int wk = tg >> 3;
    int wg0 = (tg & 7) * 2;
    int grow = bx * 32 + srow;
    float2 wv = *(const float2*)&w01[grow * 2];
    float scale = g ? wv.y : wv.x;
    const float* arow = (g ? tag : vis) + (long)grow * HDIM;
    const float* wbase = (g ? Wtag : Wvp) + by * 64;
    float* wsg = &Ws[g][0][0];

    float acc[2][4] = {{0.f,0.f,0.f,0.f},{0.f,0.f,0.f,0.f}};
    {
        float4 a0  = *(const float4*)&arow[sk4];
        float4 w0v = *(const float4*)&wbase[(long)wk * HDIM + wg0 * 4];
        float4 w1v = *(const float4*)&wbase[(long)wk * HDIM + wg0 * 4 + 4];
        As[g][0][sk4 + 0][srow] = a0.x * scale; As[g][0][sk4 + 1][srow] = a0.y * scale;
        As[g][0][sk4 + 2][srow] = a0.z * scale; As[g][0][sk4 + 3][srow] = a0.w * scale;
        *(float4*)&wsg[WIDX(wk, wg0)]     = w0v;
        *(float4*)&wsg[WIDX(wk, wg0 + 1)] = w1v;
    }
    __syncthreads();
    for (int t = 0; t < 16; ++t) {
        int buf = t & 1;
        float4 na, nw0, nw1;
        if (t < 15) {
            na  = *(const float4*)&arow[(t + 1) * KT + sk4];
            nw0 = *(const float4*)&wbase[(long)((t + 1) * KT + wk) * HDIM + wg0 * 4];
            nw1 = *(const float4*)&wbase[(long)((t + 1) * KT + wk) * HDIM + wg0 * 4 + 4];
        }
        const float* wsb = &Ws[g][buf][0];
        #pragma unroll
        for (int k = 0; k < KT; ++k) {
            float4 w = *(const float4*)&wsb[WIDX(k, ct)];
            float2 a = *(const float2*)&As[g][buf][k][rt * 2];
            acc[0][0] += a.x * w.x; acc[0][1] += a.x * w.y;
            acc[0][2] += a.x * w.z; acc[0][3] += a.x * w.w;
            acc[1][0] += a.y * w.x; acc[1][1] += a.y * w.y;
            acc[1][2] += a.y * w.z; acc[1][3] += a.y * w.w;
        }
        if (t < 15) {
            float* wsn = &Ws[g][buf ^ 1][0];
            As[g][buf ^ 1][sk4 + 0][srow] = na.x * scale; As[g][buf ^ 1][sk4 + 1][srow] = na.y * scale;
            As[g][buf ^ 1][sk4 + 2][srow] = na.z * scale; As[g][buf ^ 1][sk4 + 3][srow] = na.w * scale;
            *(float4*)&wsn[WIDX(wk, wg0)]     = nw0;
            *(float4*)&wsn[WIDX(wk, wg0 + 1)] = nw1;
        }
        __syncthreads();
    }
    if (g == 1) {
        *(float4*)&Rs[rt * 2 + 0][ct * 4] = make_float4(acc[0][0], acc[0][1], acc[0][2], acc[0][3]);
        *(float4*)&Rs[rt * 2 + 1][ct * 4] = make_float4(acc[1][0], acc[1][1], acc[1][2], acc[1][3]);
    }
    __syncthreads();
    if (g == 0) {
        float4 b1 = *(const float4*)&bvp[c0];
        float4 b2 = *(const float4*)&btag[c0];
        #pragma unroll
        for (int i = 0; i < 2; ++i) {
            int r = bx * 32 + rt * 2 + i;
            float4 rr = *(const float4*)&Rs[rt * 2 + i][ct * 4];
            float4 p = *(const float4*)&pos[(long)r * HDIM + c0];
            float4 o;
            o.x = acc[i][0] + rr.x + b1.x + b2.x + p.x;
            o.y = acc[i][1] + rr.y + b1.y + b2.y + p.y;
            o.z = acc[i][2] + rr.z + b1.z + b2.z + p.z;
            o.w = acc[i][3] + rr.w + b1.w + b2.w + p.w;
            *(float4*)&out[(long)r * HDIM + c0] = o;
        }
    }
}

// ---------------------------------------------------------------- final (lang proj fused)
__global__ __launch_bounds__(256) void final_kernel(const float* __restrict__ vis2,
                                                    const float* __restrict__ lang,
                                                    const float* __restrict__ Wts,
                                                    const float* __restrict__ bts,
                                                    const int* __restrict__ idx,
                                                    const float* __restrict__ boxes,
                                                    float* __restrict__ out) {
    __shared__ float ll[HDIM];
    __shared__ float lns[HDIM];
    __shared__ float red[4];
    __shared__ float sims[SEL];
    int b = blockIdx.x, tid = threadIdx.x;
    int lane = tid & 63, wid = tid >> 6;
    ll[tid]       = lang[b * HDIM + tid];
    ll[tid + 256] = lang[b * HDIM + tid + 256];
    __syncthreads();
    for (int h = tid; h < HDIM; h += 256) {
        float a0 = 0.f, a1 = 0.f, a2 = 0.f, a3 = 0.f;
        for (int k = 0; k < HDIM; k += 4) {
            a0 += ll[k + 0] * Wts[(long)(k + 0) * HDIM + h];
            a1 += ll[k + 1] * Wts[(long)(k + 1) * HDIM + h];
            a2 += ll[k + 2] * Wts[(long)(k + 2) * HDIM + h];
            a3 += ll[k + 3] * Wts[(long)(k + 3) * HDIM + h];
        }
        lns[h] = ((a0 + a1) + (a2 + a3)) + bts[h];
    }
    __syncthreads();
    float s = lns[tid] * lns[tid] + lns[tid + 256] * lns[tid + 256];
    for (int off = 32; off; off >>= 1) s += __shfl_down(s, off);
    if (lane == 0) red[wid] = s;
    __syncthreads();
    float sscale;
    {
        float t = red[0] + red[1] + red[2] + red[3];
        sscale = 1.0f / (sqrtf(t) + 1e-8f);
    }
    for (int j = 0; j < 8; ++j) {
        int sl = wid + j * 4;
        const float* vr = vis2 + (long)(b * SEL + sl) * HDIM;
        int k = lane * 8;
        float ss = 0.f, dot = 0.f;
        #pragma unroll
        for (int t = 0; t < 8; ++t) {
            float v = vr[k + t];
            ss += v * v;
            dot += v * lns[k + t];
        }
        for (int off = 32; off; off >>= 1) {
            ss += __shfl_down(ss, off);
            dot += __shfl_down(dot, off);
        }
        if (lane == 0) {
            float sim = dot * sscale / (sqrtf(ss) + 1e-8f);
            out[BS * 5 + b * SEL + sl] = sim;
            sims[sl] = sim;
        }
    }
    __syncthreads();
    if (tid == 0) {
        int bsi = 0; float bvv = sims[0];
        for (int sl = 1; sl < SEL; ++sl)
            if (sims[sl] > bvv) { bvv = sims[sl]; bsi = sl; }
        int g = idx[b * SEL + bsi];
        const float* bb = boxes + ((long)(b * GRID_N + g)) * A_N * CH;
        float o0 = bb[4], o1 = bb[CH + 4], o2 = bb[2 * CH + 4];
        int j = 0; float ov = o0;
        if (o1 > ov) { ov = o1; j = 1; }
        if (o2 > ov) { ov = o2; j = 2; }
        const float* sb = bb + j * CH;
        float x = sb[0], y = sb[1], w = sb[2], h = sb[3];
        float x1 = x - w * 0.5f, y1 = y - h * 0.5f;
        out[b * 5 + 0] = x1;
        out[b * 5 + 1] = y1;
        out[b * 5 + 2] = x1 + w;
        out[b * 5 + 3] = y1 + h;
        out[b * 5 + 4] = sb[4];
    }
}

// ---------------------------------------------------------------- launch
extern "C" void kernel_launch(void* const* d_in, const int* in_sizes, int n_in,
                              void* d_out, int out_size, void* d_ws, size_t ws_size,
                              hipStream_t stream) {
    const float* boxes    = (const float*)d_in[0];
    const float* x_feat   = (const float*)d_in[1];
    const float* tag_emb  = (const float*)d_in[2];
    const float* pos_emb  = (const float*)d_in[3];
    const float* lang     = (const float*)d_in[4];
    const float* W_vs     = (const float*)d_in[5];
    const float* b_vs     = (const float*)d_in[6];
    const float* W_ts     = (const float*)d_in[7];
    const float* b_ts     = (const float*)d_in[8];
    const float* W_vs_pos = (const float*)d_in[9];
    const float* b_vs_pos = (const float*)d_in[10];
    const float* W_tag    = (const float*)d_in[11];
    const float* b_tag    = (const float*)d_in[12];
    const float* W_soft   = (const float*)d_in[13];
    const float* b_soft   = (const float*)d_in[14];
    float* out = (float*)d_out;

    if (ws_size < (size_t)WS_TOTAL_FLOATS * sizeof(float)) return;

    float* wsf   = (float*)d_ws;
    int*   wsidx = (int*)d_ws;             // 1024 ints at base
    float* isel  = wsf + WS_ISEL;
    float* vis   = wsf + WS_VIS;
    float* vis2  = wsf + WS_VIS2;
    float* score = wsf + WS_SCORE;
    float* w01   = wsf + WS_W01;

    score_kernel<<<(BS * GRID_N) / 256, 256, 0, stream>>>(boxes, score);
    topk_kernel<<<BS, 256, 0, stream>>>(score, wsidx);
    gather_kernel<<<ROWS, 256, 0, stream>>>(x_feat, wsidx, isel);
    gemm1_kernel<<<dim3(32, 8), 512, 0, stream>>>(isel, W_vs, b_vs, vis);
    w01_kernel<<<ROWS / 4, 256, 0, stream>>>(vis, tag_emb, pos_emb, W_soft, b_soft, w01);
    gemm2_kernel<<<dim3(32, 8), 512, 0, stream>>>(vis, tag_emb, pos_emb, w01,
                                                  W_vs_pos, W_tag, b_vs_pos, b_tag, vis2);
    final_kernel<<<BS, 256, 0, stream>>>(vis2, lang, W_ts, b_ts, wsidx, boxes, out);
}